// Round 6
// baseline (151.328 us; speedup 1.0000x reference)
//
#include <hip/hip_runtime.h>
#include <math.h>

#define W_IMG 2048
#define H_IMG 64
#define B_IMG 8
#define C_IMG 7
#define HW_IMG (H_IMG * W_IMG)
#define NPIX (B_IMG * HW_IMG)
#define NCOPY 8

typedef float v4f __attribute__((ext_vector_type(4)));

__device__ __forceinline__ float F(unsigned u) { return __uint_as_float(u); }
#define FMAF(a,b,c) __builtin_fmaf((a),(b),(c))

// ---------------------------------------------------------------------------
// EXACT path: bit-exact glibc (<=2.39) scalar s_atanf/e_atan2f (11-coeff
// fdlibm float port, op-by-op IEEE). DO NOT TOUCH (established R4-R9).
// Used only for bin-boundary-ambiguous points, per-axis (R10).
// ---------------------------------------------------------------------------
__device__ __forceinline__ float glibc_atanf(float x) {
    const float atanhi[4] = {F(0x3eed6338u), F(0x3f490fdau), F(0x3f7b985eu), F(0x3fc90fdau)};
    const float atanlo[4] = {F(0x31ac3769u), F(0x33222168u), F(0x33140fb4u), F(0x33a22168u)};
    const float aT0 = F(0x3eaaaaabu), aT1 = F(0xbe4ccccdu), aT2 = F(0x3e124925u),
                aT3 = F(0xbde38e38u), aT4 = F(0x3dba2e6eu), aT5 = F(0xbd9d8795u),
                aT6 = F(0x3d886b35u), aT7 = F(0xbd6ef16bu), aT8 = F(0x3d4bda59u),
                aT9 = F(0xbd15a221u), aT10 = F(0x3c8569d7u);

    unsigned hx = __float_as_uint(x);
    unsigned ix = hx & 0x7fffffffu;
    if (ix >= 0x4c800000u) {
        if (ix > 0x7f800000u) return x + x;
        float v = __fadd_rn(atanhi[3], atanlo[3]);
        return (hx >> 31) ? -v : v;
    }
    int id;
    float xr = x;
    if (ix < 0x3ee00000u) {
        if (ix < 0x31000000u) return x;
        id = -1;
    } else {
        xr = fabsf(x);
        if (ix < 0x3f980000u) {
            if (ix < 0x3f300000u) {
                id = 0;
                xr = __fdiv_rn(__fsub_rn(__fmul_rn(2.0f, xr), 1.0f),
                               __fadd_rn(2.0f, xr));
            } else {
                id = 1;
                xr = __fdiv_rn(__fsub_rn(xr, 1.0f), __fadd_rn(xr, 1.0f));
            }
        } else {
            if (ix < 0x401c0000u) {
                id = 2;
                xr = __fdiv_rn(__fsub_rn(xr, 1.5f),
                               __fadd_rn(1.0f, __fmul_rn(1.5f, xr)));
            } else {
                id = 3;
                xr = __fdiv_rn(-1.0f, xr);
            }
        }
    }
    float z = __fmul_rn(xr, xr);
    float w = __fmul_rn(z, z);
    float s1 = __fmul_rn(z, __fadd_rn(aT0, __fmul_rn(w, __fadd_rn(aT2,
               __fmul_rn(w, __fadd_rn(aT4, __fmul_rn(w, __fadd_rn(aT6,
               __fmul_rn(w, __fadd_rn(aT8, __fmul_rn(w, aT10)))))))))));
    float s2 = __fmul_rn(w, __fadd_rn(aT1, __fmul_rn(w, __fadd_rn(aT3,
               __fmul_rn(w, __fadd_rn(aT5, __fmul_rn(w, __fadd_rn(aT7,
               __fmul_rn(w, aT9)))))))));
    if (id < 0) return __fsub_rn(x, __fmul_rn(x, __fadd_rn(s1, s2)));
    float zz = __fsub_rn(atanhi[id],
               __fsub_rn(__fsub_rn(__fmul_rn(xr, __fadd_rn(s1, s2)), atanlo[id]), xr));
    return (hx >> 31) ? -zz : zz;
}

__device__ __forceinline__ float glibc_atan2f(float y, float x) {
    const float pi_o_2 = F(0x3fc90fdbu);
    const float pi     = F(0x40490fdbu);
    const float pi_lo  = F(0xb3bbbd2eu);
    unsigned hx = __float_as_uint(x), hy = __float_as_uint(y);
    unsigned ix = hx & 0x7fffffffu, iy = hy & 0x7fffffffu;
    if (ix > 0x7f800000u || iy > 0x7f800000u) return x + y;
    if (hx == 0x3f800000u) return glibc_atanf(y);
    unsigned m = ((hy >> 31) & 1u) | ((hx >> 30) & 2u);
    if (iy == 0) {
        switch (m) {
            case 0: case 1: return y;
            case 2: return pi;
            default: return -pi;
        }
    }
    if (ix == 0) return (m & 1u) ? -pi_o_2 : pi_o_2;
    if (ix == 0x7f800000u) {
        if (iy == 0x7f800000u) {
            switch (m) {
                case 0: return F(0x3f490fdbu);
                case 1: return -F(0x3f490fdbu);
                case 2: return __fmul_rn(3.0f, F(0x3f490fdbu));
                default: return -__fmul_rn(3.0f, F(0x3f490fdbu));
            }
        } else {
            switch (m) {
                case 0: return 0.0f;
                case 1: return -0.0f;
                case 2: return pi;
                default: return -pi;
            }
        }
    }
    if (iy == 0x7f800000u) return (m & 1u) ? -pi_o_2 : pi_o_2;

    int k = ((int)iy - (int)ix) >> 23;
    float z;
    if (k > 26) {
        z = __fadd_rn(pi_o_2, __fmul_rn(0.5f, pi_lo));
        m &= 1u;
    } else if (k < -26 && (hx >> 31)) {
        z = 0.0f;
    } else {
        z = glibc_atanf(fabsf(__fdiv_rn(y, x)));
    }
    switch (m) {
        case 0: return z;
        case 1: return __uint_as_float(__float_as_uint(z) ^ 0x80000000u);
        case 2: return __fsub_rn(pi, __fsub_rn(z, pi_lo));
        default: return __fsub_rn(__fsub_rn(z, pi_lo), pi);
    }
}

#define H0F   ((float)(-3.14159265358979323846))
#define SPANH ((float)( 6.28318530717958647692))
#define V0F   ((float)(-3.0 * 3.14159265358979323846 / 180.0))
#define SPANV ((float)((25.0 * 3.14159265358979323846 / 180.0) - \
                       (-3.0 * 3.14159265358979323846 / 180.0)))
#define RHc   (1.0f / SPANH)
#define RVc   (1.0f / SPANV)

__device__ __forceinline__ float norm_r(float x, float y, float z) {
    return __fsqrt_rn(FMAF(z, z, FMAF(y, y, __fmul_rn(x, x))));
}

// ---------------------------------------------------------------------------
// FAST path: minimax atan on [0,1] (6 coeffs, |err| <~ 2.4e-5 rad).
// ---------------------------------------------------------------------------
__device__ __forceinline__ float atan01(float t) {
    float q = t * t;
    float p =          -0.0117212f;
    p = FMAF(q, p,      0.05265332f);
    p = FMAF(q, p,     -0.11643287f);
    p = FMAF(q, p,      0.19354346f);
    p = FMAF(q, p,     -0.33262347f);
    p = FMAF(q, p,      0.99997726f);
    return t * p;
}

// Margins in bin units (bin width = 1.0). Error budget 1.5e-4 rad covers the
// 2.4e-5 poly error + arith rounding; rcp/rsq substitution adds ~2e-7 rad.
// u: 1.5e-4 rad * RH * 2048 = 0.049 -> 0.06.  v: 1.5e-4 * RV * 64 = 0.0197 -> 0.025.
#define MU 0.06f
#define MV 0.025f

// Per-point resolve, fast/exact decision SPLIT PER AXIS (R10, counter-verified:
// -17% absolute VALU cycles vs whole-point split).
//  - unambiguous axis: fast bin provably equals the exact-pipeline bin.
//  - ambiguous axis: op-exact glibc replica for THAT angle only.
// NaN-safety: NaN in uf/vf makes ulo==uhi false -> exact path decides.
__device__ __forceinline__ int resolve_pix(float bsf, float x, float y, float z) {
    float r  = norm_r(x, y, z);
    float zr = __fdiv_rn(z, fmaxf(r, 1e-5f));   // exact: feeds exact path
    // Guaranteed v-reject (margin ~7e-5 rad >> all pipeline error).
    if (zr > 0.05240f || zr < -0.42270f) return -1;

    // fast angles (rcp/rsq variants, margin-covered)
    float ax = fabsf(x), ay = fabsf(y);
    float mx = fmaxf(ax, ay), mn = fminf(ax, ay);
    float t  = (mx > 0.0f) ? (mn * __builtin_amdgcn_rcpf(mx)) : 0.0f;
    float a  = atan01(t);
    if (ay > ax) a = 1.57079632679f - a;
    if (x < 0.0f) a = 3.14159265359f - a;
    float th = (y < 0.0f) ? a : -a;             // ~= -atan2(y,x)

    float az  = fabsf(zr);
    float arg = az * __builtin_amdgcn_rsqf(FMAF(-zr, zr, 1.0f));
    float pa  = atan01(arg);
    float ph  = (zr >= 0.0f) ? -pa : pa;        // ~= -asin(zr)

    float uf = (th - H0F) * (RHc * (float)W_IMG);
    float vf = (ph - V0F) * (RVc * (float)H_IMG);
    float ulo = floorf(uf - MU), uhi = floorf(uf + MU);
    float vlo = floorf(vf - MV), vhi = floorf(vf + MV);

    int u, v;
    if (ulo == uhi) {
        u = (int)ulo;
    } else {
        float theta = -glibc_atan2f(y, x);
        float u_n = __fmul_rn(__fsub_rn(theta, H0F), RHc);
        if (!(u_n >= 0.0f && u_n < 1.0f)) return -1;
        u = (int)__fmul_rn(u_n, (float)W_IMG);
    }
    if (u < 0 || u >= W_IMG) return -1;

    if (vlo == vhi) {
        v = (int)vlo;
    } else {
        float s   = __fsqrt_rn(FMAF(-zr, zr, 1.0f));
        float d   = __fadd_rn(1.0f, s);
        float phi = -__fmul_rn(2.0f, glibc_atan2f(zr, d));
        float v_n = __fmul_rn(__fsub_rn(phi, V0F), RVc);
        if (!(v_n >= 0.0f && v_n < 1.0f)) return -1;
        v = (int)__fmul_rn(v_n, (float)H_IMG);
    }
    if (v < 0 || v >= H_IMG) return -1;

    return (((int)bsf) * H_IMG + v) * W_IMG + u;
}

// Physical XCD id (0-7), HW-verified on gfx950 (learn_hip m09). Wave-uniform
// SGPR read, ~free. Masked to 3 bits for OOB safety.
__device__ __forceinline__ int xcc_id() {
    unsigned x;
    asm volatile("s_getreg_b32 %0, hwreg(HW_REG_XCC_ID)" : "=s"(x));
    return (int)(x & 7u);
}

// ---------------------------------------------------------------------------
// R15 scatter: R14 skeleton (no filter, 1 pt/thread, full grid) + per-XCD
// winner copies + WORKGROUP-SCOPE relaxed atomic_fetch_max.
// Evidence chain: R14 showed deleting the filter swaps 52MB of reads for
// ~600K extra atomics at ~equal cost -> both traverse the same path: HIP's
// default atomicMax is device-scope (sc1) and executes at the memory-side
// coherence point (~900cy fabric RMW). R13's per-XCD copies failed because
// the EXECUTION POINT, not the address, was remote. Scope demotion fixes
// that: an atomic without sc1 executes at the issuing XCD's own L2 (TCP
// forwards all atomics to TCC; scope decides whether it must go past L2).
// Safety: every writer of copy c is a workgroup on XCD c; all share that
// L2; RMW atomicity is provided by the L2 bank. Each 4MB copy fits the 4MB
// XCD L2. End-of-dispatch release flushes dirty L2 -> write_output (next
// dispatch) sees final values. Empty = negative (harness 0xAA-poisons d_ws
// each launch); max is commutative -> idempotent across replays.
// ---------------------------------------------------------------------------
#define SC_TPB 256

__global__ void __launch_bounds__(SC_TPB)
scatter_winner8(const float* __restrict__ pts, int* __restrict__ winner, int n) {
    int t = blockIdx.x * blockDim.x + threadIdx.x;
    if (t >= n) return;
    const float* q = pts + (size_t)t * 5;
    int pix = resolve_pix(q[0], q[1], q[2], q[3]);
    if (pix < 0) return;
    int* wc = winner + (size_t)xcc_id() * NPIX + pix;
    // XCD-L2-local atomic (no sc1): fire-and-forget, no fabric round trip.
    __hip_atomic_fetch_max(wc, t, __ATOMIC_RELAXED, __HIP_MEMORY_SCOPE_WORKGROUP);
}

// Fallback (ws too small for 8 copies): exact R14 single-copy device scatter.
__global__ void __launch_bounds__(SC_TPB)
scatter_winner1(const float* __restrict__ pts, int* __restrict__ winner, int n) {
    int t = blockIdx.x * blockDim.x + threadIdx.x;
    if (t >= n) return;
    const float* q = pts + (size_t)t * 5;
    int pix = resolve_pix(q[0], q[1], q[2], q[3]);
    if (pix < 0) return;
    atomicMax(&winner[pix], t);
}

// 4 pixels/thread: NC-way winner merge (coalesced int4 per copy), batched
// gathers, fast-path features (err 2.4e-5 << 3.02 threshold), 7 NT float4
// channel stores. (R13's NC-template, correctness-proven.)
__device__ __forceinline__ void fast_angles(float x, float y, float zr,
                                            float* theta, float* phi) {
    float ax = fabsf(x), ay = fabsf(y);
    float mx = fmaxf(ax, ay), mn = fminf(ax, ay);
    float t = (mx > 0.0f) ? (mn / mx) : 0.0f;
    float a = atan01(t);
    if (ay > ax) a = 1.57079632679f - a;
    if (x < 0.0f) a = 3.14159265359f - a;
    *theta = (y < 0.0f) ? a : -a;               // == -atan2(y,x)

    float az  = fabsf(zr);
    float arg = az / __fsqrt_rn(FMAF(-zr, zr, 1.0f));
    float pa  = atan01(arg);
    *phi = (zr >= 0.0f) ? -pa : pa;             // == -asin(zr)
}

template <int NC>
__global__ void __launch_bounds__(256, 4)
write_output_t(const float* __restrict__ pts, const int* __restrict__ winner,
               float* __restrict__ out) {
    int t  = blockIdx.x * blockDim.x + threadIdx.x;
    int p0 = t * 4;
    if (p0 >= NPIX) return;

    int4 w4 = *(const int4*)(winner + p0);
#pragma unroll
    for (int c = 1; c < NC; ++c) {
        int4 o = *(const int4*)(winner + (size_t)c * NPIX + p0);
        w4.x = max(w4.x, o.x); w4.y = max(w4.y, o.y);
        w4.z = max(w4.z, o.z); w4.w = max(w4.w, o.w);
    }
    int wis[4] = {w4.x, w4.y, w4.z, w4.w};

    float qx[4], qy[4], qz[4], qi[4];
#pragma unroll
    for (int k = 0; k < 4; ++k) {
        if (wis[k] >= 0) {
            const float* q = pts + (size_t)wis[k] * 5;
            qx[k] = q[1]; qy[k] = q[2]; qz[k] = q[3]; qi[k] = q[4];
        }
    }

    float fc[C_IMG][4];
#pragma unroll
    for (int c = 0; c < C_IMG; ++c)
#pragma unroll
        for (int k = 0; k < 4; ++k) fc[c][k] = 0.f;

#pragma unroll
    for (int k = 0; k < 4; ++k) {
        if (wis[k] >= 0) {
            float x = qx[k], y = qy[k], z = qz[k];
            float r  = norm_r(x, y, z);
            float zr = __fdiv_rn(z, fmaxf(r, 1e-5f));
            float th, ph;
            fast_angles(x, y, zr, &th, &ph);
            fc[0][k] = x; fc[1][k] = y; fc[2][k] = z;
            fc[3][k] = r; fc[4][k] = th; fc[5][k] = ph;
            fc[6][k] = qi[k];
        }
    }

    int b  = p0 >> 17;             // / HW_IMG (131072)
    int hw = p0 & (HW_IMG - 1);
    size_t base = (size_t)b * C_IMG * HW_IMG + hw;
#pragma unroll
    for (int c = 0; c < C_IMG; ++c) {
        v4f v = {fc[c][0], fc[c][1], fc[c][2], fc[c][3]};
        __builtin_nontemporal_store(v, (v4f*)(out + base + (size_t)c * HW_IMG));
    }
}

extern "C" void kernel_launch(void* const* d_in, const int* in_sizes, int n_in,
                              void* d_out, int out_size, void* d_ws, size_t ws_size,
                              hipStream_t stream) {
    const float* pts = (const float*)d_in[0];
    int n = in_sizes[0] / 5;
    if (n <= 0) return;
    int* winner = (int*)d_ws;   // 0xAA-poisoned each launch = negative = empty
    float* out = (float*)d_out;

    int blocks = (n + SC_TPB - 1) / SC_TPB;
    int pthreads = NPIX / 4;
    int pblocks = (pthreads + 255) / 256;

    if (ws_size >= (size_t)NCOPY * NPIX * sizeof(int)) {
        scatter_winner8<<<blocks, SC_TPB, 0, stream>>>(pts, winner, n);
        write_output_t<NCOPY><<<pblocks, 256, 0, stream>>>(pts, winner, out);
    } else {
        scatter_winner1<<<blocks, SC_TPB, 0, stream>>>(pts, winner, n);
        write_output_t<1><<<pblocks, 256, 0, stream>>>(pts, winner, out);
    }
}

// Round 7
// 147.002 us; speedup vs baseline: 1.0294x; 1.0294x over previous
//
#include <hip/hip_runtime.h>
#include <math.h>

#define W_IMG 2048
#define H_IMG 64
#define B_IMG 8
#define C_IMG 7
#define HW_IMG (H_IMG * W_IMG)
#define NPIX (B_IMG * HW_IMG)

typedef float v4f __attribute__((ext_vector_type(4)));

__device__ __forceinline__ float F(unsigned u) { return __uint_as_float(u); }
#define FMAF(a,b,c) __builtin_fmaf((a),(b),(c))

// ---------------------------------------------------------------------------
// EXACT path: bit-exact glibc (<=2.39) scalar s_atanf/e_atan2f (11-coeff
// fdlibm float port, op-by-op IEEE). DO NOT TOUCH (established R4-R9).
// Used only for bin-boundary-ambiguous points, per-axis (R10).
// ---------------------------------------------------------------------------
__device__ __forceinline__ float glibc_atanf(float x) {
    const float atanhi[4] = {F(0x3eed6338u), F(0x3f490fdau), F(0x3f7b985eu), F(0x3fc90fdau)};
    const float atanlo[4] = {F(0x31ac3769u), F(0x33222168u), F(0x33140fb4u), F(0x33a22168u)};
    const float aT0 = F(0x3eaaaaabu), aT1 = F(0xbe4ccccdu), aT2 = F(0x3e124925u),
                aT3 = F(0xbde38e38u), aT4 = F(0x3dba2e6eu), aT5 = F(0xbd9d8795u),
                aT6 = F(0x3d886b35u), aT7 = F(0xbd6ef16bu), aT8 = F(0x3d4bda59u),
                aT9 = F(0xbd15a221u), aT10 = F(0x3c8569d7u);

    unsigned hx = __float_as_uint(x);
    unsigned ix = hx & 0x7fffffffu;
    if (ix >= 0x4c800000u) {
        if (ix > 0x7f800000u) return x + x;
        float v = __fadd_rn(atanhi[3], atanlo[3]);
        return (hx >> 31) ? -v : v;
    }
    int id;
    float xr = x;
    if (ix < 0x3ee00000u) {
        if (ix < 0x31000000u) return x;
        id = -1;
    } else {
        xr = fabsf(x);
        if (ix < 0x3f980000u) {
            if (ix < 0x3f300000u) {
                id = 0;
                xr = __fdiv_rn(__fsub_rn(__fmul_rn(2.0f, xr), 1.0f),
                               __fadd_rn(2.0f, xr));
            } else {
                id = 1;
                xr = __fdiv_rn(__fsub_rn(xr, 1.0f), __fadd_rn(xr, 1.0f));
            }
        } else {
            if (ix < 0x401c0000u) {
                id = 2;
                xr = __fdiv_rn(__fsub_rn(xr, 1.5f),
                               __fadd_rn(1.0f, __fmul_rn(1.5f, xr)));
            } else {
                id = 3;
                xr = __fdiv_rn(-1.0f, xr);
            }
        }
    }
    float z = __fmul_rn(xr, xr);
    float w = __fmul_rn(z, z);
    float s1 = __fmul_rn(z, __fadd_rn(aT0, __fmul_rn(w, __fadd_rn(aT2,
               __fmul_rn(w, __fadd_rn(aT4, __fmul_rn(w, __fadd_rn(aT6,
               __fmul_rn(w, __fadd_rn(aT8, __fmul_rn(w, aT10)))))))))));
    float s2 = __fmul_rn(w, __fadd_rn(aT1, __fmul_rn(w, __fadd_rn(aT3,
               __fmul_rn(w, __fadd_rn(aT5, __fmul_rn(w, __fadd_rn(aT7,
               __fmul_rn(w, aT9)))))))));
    if (id < 0) return __fsub_rn(x, __fmul_rn(x, __fadd_rn(s1, s2)));
    float zz = __fsub_rn(atanhi[id],
               __fsub_rn(__fsub_rn(__fmul_rn(xr, __fadd_rn(s1, s2)), atanlo[id]), xr));
    return (hx >> 31) ? -zz : zz;
}

__device__ __forceinline__ float glibc_atan2f(float y, float x) {
    const float pi_o_2 = F(0x3fc90fdbu);
    const float pi     = F(0x40490fdbu);
    const float pi_lo  = F(0xb3bbbd2eu);
    unsigned hx = __float_as_uint(x), hy = __float_as_uint(y);
    unsigned ix = hx & 0x7fffffffu, iy = hy & 0x7fffffffu;
    if (ix > 0x7f800000u || iy > 0x7f800000u) return x + y;
    if (hx == 0x3f800000u) return glibc_atanf(y);
    unsigned m = ((hy >> 31) & 1u) | ((hx >> 30) & 2u);
    if (iy == 0) {
        switch (m) {
            case 0: case 1: return y;
            case 2: return pi;
            default: return -pi;
        }
    }
    if (ix == 0) return (m & 1u) ? -pi_o_2 : pi_o_2;
    if (ix == 0x7f800000u) {
        if (iy == 0x7f800000u) {
            switch (m) {
                case 0: return F(0x3f490fdbu);
                case 1: return -F(0x3f490fdbu);
                case 2: return __fmul_rn(3.0f, F(0x3f490fdbu));
                default: return -__fmul_rn(3.0f, F(0x3f490fdbu));
            }
        } else {
            switch (m) {
                case 0: return 0.0f;
                case 1: return -0.0f;
                case 2: return pi;
                default: return -pi;
            }
        }
    }
    if (iy == 0x7f800000u) return (m & 1u) ? -pi_o_2 : pi_o_2;

    int k = ((int)iy - (int)ix) >> 23;
    float z;
    if (k > 26) {
        z = __fadd_rn(pi_o_2, __fmul_rn(0.5f, pi_lo));
        m &= 1u;
    } else if (k < -26 && (hx >> 31)) {
        z = 0.0f;
    } else {
        z = glibc_atanf(fabsf(__fdiv_rn(y, x)));
    }
    switch (m) {
        case 0: return z;
        case 1: return __uint_as_float(__float_as_uint(z) ^ 0x80000000u);
        case 2: return __fsub_rn(pi, __fsub_rn(z, pi_lo));
        default: return __fsub_rn(__fsub_rn(z, pi_lo), pi);
    }
}

#define H0F   ((float)(-3.14159265358979323846))
#define SPANH ((float)( 6.28318530717958647692))
#define V0F   ((float)(-3.0 * 3.14159265358979323846 / 180.0))
#define SPANV ((float)((25.0 * 3.14159265358979323846 / 180.0) - \
                       (-3.0 * 3.14159265358979323846 / 180.0)))
#define RHc   (1.0f / SPANH)
#define RVc   (1.0f / SPANV)

__device__ __forceinline__ float norm_r(float x, float y, float z) {
    return __fsqrt_rn(FMAF(z, z, FMAF(y, y, __fmul_rn(x, x))));
}

// ---------------------------------------------------------------------------
// FAST path v2 (R16): range-reduced Taylor atan. Reduce at tan(pi/8)=0.41421:
//   atan(t) = pi/4 + atan((t-1)/(t+1)),  reduced |s| <= 0.41422.
// Taylor-6 (odd powers through s^11) truncation err <= 0.41422^13/13 = 8.2e-7
// rad (alternating series). Coefficients are EXACT Taylor terms (no invented
// minimax). + ~4ulp Horner rounding + 1ulp rcp -> total atan err <= ~1.1e-6.
// Whole-angle error (incl. pi/2, pi assembly rounding) <= ~1.9e-6 rad.
// ---------------------------------------------------------------------------
__device__ __forceinline__ float fast_atan01(float t) {
    bool red = t > 0.41421357f;
    float s  = red ? ((t - 1.0f) * __builtin_amdgcn_rcpf(t + 1.0f)) : t;
    float q  = s * s;
    float p  =          -0.0909090909f;   // -1/11
    p = FMAF(q, p,       0.1111111111f);  //  1/9
    p = FMAF(q, p,      -0.1428571429f);  // -1/7
    p = FMAF(q, p,       0.2f);           //  1/5
    p = FMAF(q, p,      -0.3333333333f);  // -1/3
    p = FMAF(q, p,       1.0f);
    float a = s * p;
    return red ? (0.78539816339f + a) : a;
}

// R16 margins (bin units). Error budget per axis:
//  u: angle 1.9e-6 rad * (2048/2pi)=326/rad = 6.2e-4 bins
//     + binning arith (3ulp rel on uf<=2048 + expr-shape vs exact) ~ 3.7e-4
//     -> <= 1.0e-3 bins.  MU = 0.003 (3x slack).  Ambiguity 12% -> 0.6%/pt.
//  v: angle 1.9e-6 * (64/0.4887)=131/rad = 2.5e-4 + arith ~4e-5 -> <=3e-4.
//     MV = 0.001 (3x slack).  Ambiguity 5% -> 0.2%/pt.
// Wave-level glibc execution: u 100%->~32%, v 100%->~12% of waves.
#define MU 0.003f
#define MV 0.001f

// Per-point resolve, fast/exact SPLIT PER AXIS (R10, counter-verified).
//  - unambiguous axis: fast bin provably equals the exact-pipeline bin
//    (interval [f-M, f+M] inside one bin + |fast - exact_input| < M).
//  - ambiguous axis: op-exact glibc replica for THAT angle only; the
//    v-branch recomputes the bit-exact __fdiv_rn zr it requires.
// NaN-safety: NaN in uf/vf makes ulo==uhi false -> exact path decides.
__device__ __forceinline__ int resolve_pix(float bsf, float x, float y, float z) {
    float r  = norm_r(x, y, z);
    // Fast zr via rcp (1ulp, ~3e-8 abs; margins have 3x slack over budget
    // INCLUDING this). Exact fdiv zr recomputed only in the v-exact branch.
    float zr = z * __builtin_amdgcn_rcpf(fmaxf(r, 1e-5f));
    // Guaranteed v-reject (threshold margin ~7e-5 rad >> all pipeline error).
    if (zr > 0.05240f || zr < -0.42270f) return -1;

    // fast angles
    float ax = fabsf(x), ay = fabsf(y);
    float mx = fmaxf(ax, ay), mn = fminf(ax, ay);
    float t  = (mx > 0.0f) ? (mn * __builtin_amdgcn_rcpf(mx)) : 0.0f;
    float a  = fast_atan01(t);
    if (ay > ax) a = 1.5707963268f - a;
    if (x < 0.0f) a = 3.1415926536f - a;
    float th = (y < 0.0f) ? a : -a;             // ~= -atan2(y,x)

    float az  = fabsf(zr);
    float arg = az * __builtin_amdgcn_rsqf(FMAF(-zr, zr, 1.0f));
    float pa  = fast_atan01(arg);
    float ph  = (zr >= 0.0f) ? -pa : pa;        // ~= -asin(zr)

    float uf = (th - H0F) * (RHc * (float)W_IMG);
    float vf = (ph - V0F) * (RVc * (float)H_IMG);
    float ulo = floorf(uf - MU), uhi = floorf(uf + MU);
    float vlo = floorf(vf - MV), vhi = floorf(vf + MV);

    int u, v;
    if (ulo == uhi) {
        u = (int)ulo;
    } else {
        float theta = -glibc_atan2f(y, x);
        float u_n = __fmul_rn(__fsub_rn(theta, H0F), RHc);
        if (!(u_n >= 0.0f && u_n < 1.0f)) return -1;
        u = (int)__fmul_rn(u_n, (float)W_IMG);
    }
    if (u < 0 || u >= W_IMG) return -1;

    if (vlo == vhi) {
        v = (int)vlo;
    } else {
        // Recompute the BIT-EXACT zr the established exact pipeline uses.
        float zre = __fdiv_rn(z, fmaxf(r, 1e-5f));
        float s   = __fsqrt_rn(FMAF(-zre, zre, 1.0f));
        float d   = __fadd_rn(1.0f, s);
        float phi = -__fmul_rn(2.0f, glibc_atan2f(zre, d));
        float v_n = __fmul_rn(__fsub_rn(phi, V0F), RVc);
        if (!(v_n >= 0.0f && v_n < 1.0f)) return -1;
        v = (int)__fmul_rn(v_n, (float)H_IMG);
    }
    if (v < 0 || v >= H_IMG) return -1;

    return (((int)bsf) * H_IMG + v) * W_IMG + u;
}

// ---------------------------------------------------------------------------
// R16 scatter: R14 skeleton UNCHANGED (1 pt/thread, full grid, reverse order,
// single winner copy, no filter, fire-and-forget device atomicMax). The ONLY
// change this round is the resolve_pix VALU thinning above. R14 reference:
// 61us, VALUBusy 22% (= 1055 VALU-issue cy/wave: glibc ran in ~100% of waves
// because 12%/pt ambiguity => every 64-lane wave had ambiguous lanes).
// ---------------------------------------------------------------------------
#define SC_TPB 256

__global__ void __launch_bounds__(SC_TPB)
scatter_winner(const float* __restrict__ pts, int* __restrict__ winner, int n) {
    int t = blockIdx.x * blockDim.x + threadIdx.x;
    if (t >= n) return;
    int i = n - 1 - t;
    const float* q = pts + (size_t)i * 5;
    int pix = resolve_pix(q[0], q[1], q[2], q[3]);
    if (pix < 0) return;
    atomicMax(&winner[pix], i);    // non-returning: wave does not wait
}

// 4 pixels/thread: int4 winner load, batched gathers, fast-path features
// (err 2.4e-5 << 3.02 threshold), 7 NT float4 channel stores.
// Byte-identical to the measured-good R0/R14 version.
__device__ __forceinline__ float atan01_legacy(float t) {
    float q = t * t;
    float p =          -0.0117212f;
    p = FMAF(q, p,      0.05265332f);
    p = FMAF(q, p,     -0.11643287f);
    p = FMAF(q, p,      0.19354346f);
    p = FMAF(q, p,     -0.33262347f);
    p = FMAF(q, p,      0.99997726f);
    return t * p;
}

__device__ __forceinline__ void fast_angles(float x, float y, float zr,
                                            float* theta, float* phi) {
    float ax = fabsf(x), ay = fabsf(y);
    float mx = fmaxf(ax, ay), mn = fminf(ax, ay);
    float t = (mx > 0.0f) ? (mn / mx) : 0.0f;
    float a = atan01_legacy(t);
    if (ay > ax) a = 1.57079632679f - a;
    if (x < 0.0f) a = 3.14159265359f - a;
    *theta = (y < 0.0f) ? a : -a;               // == -atan2(y,x)

    float az  = fabsf(zr);
    float arg = az / __fsqrt_rn(FMAF(-zr, zr, 1.0f));
    float pa  = atan01_legacy(arg);
    *phi = (zr >= 0.0f) ? -pa : pa;             // == -asin(zr)
}

__global__ void __launch_bounds__(256, 4)
write_output(const float* __restrict__ pts, const int* __restrict__ winner,
             float* __restrict__ out) {
    int t  = blockIdx.x * blockDim.x + threadIdx.x;
    int p0 = t * 4;
    if (p0 >= NPIX) return;

    int4 w4 = *(const int4*)(winner + p0);
    int wis[4] = {w4.x, w4.y, w4.z, w4.w};

    float qx[4], qy[4], qz[4], qi[4];
#pragma unroll
    for (int k = 0; k < 4; ++k) {
        if (wis[k] >= 0) {
            const float* q = pts + (size_t)wis[k] * 5;
            qx[k] = q[1]; qy[k] = q[2]; qz[k] = q[3]; qi[k] = q[4];
        }
    }

    float fc[C_IMG][4];
#pragma unroll
    for (int c = 0; c < C_IMG; ++c)
#pragma unroll
        for (int k = 0; k < 4; ++k) fc[c][k] = 0.f;

#pragma unroll
    for (int k = 0; k < 4; ++k) {
        if (wis[k] >= 0) {
            float x = qx[k], y = qy[k], z = qz[k];
            float r  = norm_r(x, y, z);
            float zr = __fdiv_rn(z, fmaxf(r, 1e-5f));
            float th, ph;
            fast_angles(x, y, zr, &th, &ph);
            fc[0][k] = x; fc[1][k] = y; fc[2][k] = z;
            fc[3][k] = r; fc[4][k] = th; fc[5][k] = ph;
            fc[6][k] = qi[k];
        }
    }

    int b  = p0 >> 17;             // / HW_IMG (131072)
    int hw = p0 & (HW_IMG - 1);
    size_t base = (size_t)b * C_IMG * HW_IMG + hw;
#pragma unroll
    for (int c = 0; c < C_IMG; ++c) {
        v4f v = {fc[c][0], fc[c][1], fc[c][2], fc[c][3]};
        __builtin_nontemporal_store(v, (v4f*)(out + base + (size_t)c * HW_IMG));
    }
}

extern "C" void kernel_launch(void* const* d_in, const int* in_sizes, int n_in,
                              void* d_out, int out_size, void* d_ws, size_t ws_size,
                              hipStream_t stream) {
    const float* pts = (const float*)d_in[0];
    int n = in_sizes[0] / 5;
    if (n <= 0) return;
    int* winner = (int*)d_ws;   // 0xAA-poisoned each launch = negative = empty
    float* out = (float*)d_out;

    int blocks = (n + SC_TPB - 1) / SC_TPB;
    scatter_winner<<<blocks, SC_TPB, 0, stream>>>(pts, winner, n);

    int pthreads = NPIX / 4;
    write_output<<<(pthreads + 255) / 256, 256, 0, stream>>>(pts, winner, out);
}

// Round 9
// 140.965 us; speedup vs baseline: 1.0735x; 1.0428x over previous
//
#include <hip/hip_runtime.h>
#include <math.h>

#define W_IMG 2048
#define H_IMG 64
#define B_IMG 8
#define C_IMG 7
#define HW_IMG (H_IMG * W_IMG)
#define NPIX (B_IMG * HW_IMG)

typedef float v4f __attribute__((ext_vector_type(4)));

__device__ __forceinline__ float F(unsigned u) { return __uint_as_float(u); }
#define FMAF(a,b,c) __builtin_fmaf((a),(b),(c))

// ---------------------------------------------------------------------------
// EXACT path: bit-exact glibc (<=2.39) scalar s_atanf/e_atan2f (11-coeff
// fdlibm float port, op-by-op IEEE). DO NOT TOUCH (established R4-R9).
// Used only for bin-boundary-ambiguous points, per-axis (R10).
// ---------------------------------------------------------------------------
__device__ __forceinline__ float glibc_atanf(float x) {
    const float atanhi[4] = {F(0x3eed6338u), F(0x3f490fdau), F(0x3f7b985eu), F(0x3fc90fdau)};
    const float atanlo[4] = {F(0x31ac3769u), F(0x33222168u), F(0x33140fb4u), F(0x33a22168u)};
    const float aT0 = F(0x3eaaaaabu), aT1 = F(0xbe4ccccdu), aT2 = F(0x3e124925u),
                aT3 = F(0xbde38e38u), aT4 = F(0x3dba2e6eu), aT5 = F(0xbd9d8795u),
                aT6 = F(0x3d886b35u), aT7 = F(0xbd6ef16bu), aT8 = F(0x3d4bda59u),
                aT9 = F(0xbd15a221u), aT10 = F(0x3c8569d7u);

    unsigned hx = __float_as_uint(x);
    unsigned ix = hx & 0x7fffffffu;
    if (ix >= 0x4c800000u) {
        if (ix > 0x7f800000u) return x + x;
        float v = __fadd_rn(atanhi[3], atanlo[3]);
        return (hx >> 31) ? -v : v;
    }
    int id;
    float xr = x;
    if (ix < 0x3ee00000u) {
        if (ix < 0x31000000u) return x;
        id = -1;
    } else {
        xr = fabsf(x);
        if (ix < 0x3f980000u) {
            if (ix < 0x3f300000u) {
                id = 0;
                xr = __fdiv_rn(__fsub_rn(__fmul_rn(2.0f, xr), 1.0f),
                               __fadd_rn(2.0f, xr));
            } else {
                id = 1;
                xr = __fdiv_rn(__fsub_rn(xr, 1.0f), __fadd_rn(xr, 1.0f));
            }
        } else {
            if (ix < 0x401c0000u) {
                id = 2;
                xr = __fdiv_rn(__fsub_rn(xr, 1.5f),
                               __fadd_rn(1.0f, __fmul_rn(1.5f, xr)));
            } else {
                id = 3;
                xr = __fdiv_rn(-1.0f, xr);
            }
        }
    }
    float z = __fmul_rn(xr, xr);
    float w = __fmul_rn(z, z);
    float s1 = __fmul_rn(z, __fadd_rn(aT0, __fmul_rn(w, __fadd_rn(aT2,
               __fmul_rn(w, __fadd_rn(aT4, __fmul_rn(w, __fadd_rn(aT6,
               __fmul_rn(w, __fadd_rn(aT8, __fmul_rn(w, aT10)))))))))));
    float s2 = __fmul_rn(w, __fadd_rn(aT1, __fmul_rn(w, __fadd_rn(aT3,
               __fmul_rn(w, __fadd_rn(aT5, __fmul_rn(w, __fadd_rn(aT7,
               __fmul_rn(w, aT9)))))))));
    if (id < 0) return __fsub_rn(x, __fmul_rn(x, __fadd_rn(s1, s2)));
    float zz = __fsub_rn(atanhi[id],
               __fsub_rn(__fsub_rn(__fmul_rn(xr, __fadd_rn(s1, s2)), atanlo[id]), xr));
    return (hx >> 31) ? -zz : zz;
}

__device__ __forceinline__ float glibc_atan2f(float y, float x) {
    const float pi_o_2 = F(0x3fc90fdbu);
    const float pi     = F(0x40490fdbu);
    const float pi_lo  = F(0xb3bbbd2eu);
    unsigned hx = __float_as_uint(x), hy = __float_as_uint(y);
    unsigned ix = hx & 0x7fffffffu, iy = hy & 0x7fffffffu;
    if (ix > 0x7f800000u || iy > 0x7f800000u) return x + y;
    if (hx == 0x3f800000u) return glibc_atanf(y);
    unsigned m = ((hy >> 31) & 1u) | ((hx >> 30) & 2u);
    if (iy == 0) {
        switch (m) {
            case 0: case 1: return y;
            case 2: return pi;
            default: return -pi;
        }
    }
    if (ix == 0) return (m & 1u) ? -pi_o_2 : pi_o_2;
    if (ix == 0x7f800000u) {
        if (iy == 0x7f800000u) {
            switch (m) {
                case 0: return F(0x3f490fdbu);
                case 1: return -F(0x3f490fdbu);
                case 2: return __fmul_rn(3.0f, F(0x3f490fdbu));
                default: return -__fmul_rn(3.0f, F(0x3f490fdbu));
            }
        } else {
            switch (m) {
                case 0: return 0.0f;
                case 1: return -0.0f;
                case 2: return pi;
                default: return -pi;
            }
        }
    }
    if (iy == 0x7f800000u) return (m & 1u) ? -pi_o_2 : pi_o_2;

    int k = ((int)iy - (int)ix) >> 23;
    float z;
    if (k > 26) {
        z = __fadd_rn(pi_o_2, __fmul_rn(0.5f, pi_lo));
        m &= 1u;
    } else if (k < -26 && (hx >> 31)) {
        z = 0.0f;
    } else {
        z = glibc_atanf(fabsf(__fdiv_rn(y, x)));
    }
    switch (m) {
        case 0: return z;
        case 1: return __uint_as_float(__float_as_uint(z) ^ 0x80000000u);
        case 2: return __fsub_rn(pi, __fsub_rn(z, pi_lo));
        default: return __fsub_rn(__fsub_rn(z, pi_lo), pi);
    }
}

#define H0F   ((float)(-3.14159265358979323846))
#define SPANH ((float)( 6.28318530717958647692))
#define V0F   ((float)(-3.0 * 3.14159265358979323846 / 180.0))
#define SPANV ((float)((25.0 * 3.14159265358979323846 / 180.0) - \
                       (-3.0 * 3.14159265358979323846 / 180.0)))
#define RHc   (1.0f / SPANH)
#define RVc   (1.0f / SPANV)

__device__ __forceinline__ float norm_r(float x, float y, float z) {
    return __fsqrt_rn(FMAF(z, z, FMAF(y, y, __fmul_rn(x, x))));
}

// ---------------------------------------------------------------------------
// FAST path v2 (R16): range-reduced Taylor atan. Reduce at tan(pi/8)=0.41421:
//   atan(t) = pi/4 + atan((t-1)/(t+1)),  reduced |s| <= 0.41422.
// Taylor-6 truncation err <= 0.41422^13/13 = 8.2e-7 rad; + Horner/rcp
// rounding -> whole-angle error <= ~1.9e-6 rad.
// ---------------------------------------------------------------------------
__device__ __forceinline__ float fast_atan01(float t) {
    bool red = t > 0.41421357f;
    float s  = red ? ((t - 1.0f) * __builtin_amdgcn_rcpf(t + 1.0f)) : t;
    float q  = s * s;
    float p  =          -0.0909090909f;   // -1/11
    p = FMAF(q, p,       0.1111111111f);  //  1/9
    p = FMAF(q, p,      -0.1428571429f);  // -1/7
    p = FMAF(q, p,       0.2f);           //  1/5
    p = FMAF(q, p,      -0.3333333333f);  // -1/3
    p = FMAF(q, p,       1.0f);
    float a = s * p;
    return red ? (0.78539816339f + a) : a;
}

// R16 margins (bin units): budget u <= 1.0e-3 bins -> MU=0.003 (3x slack),
// v <= 3e-4 -> MV=0.001. Ambiguity: u 0.6%/pt, v 0.2%/pt (wave-level glibc
// execution ~32%/~12% of waves).
#define MU 0.003f
#define MV 0.001f

// Per-point resolve, fast/exact SPLIT PER AXIS (R10, counter-verified).
// NaN-safety: NaN in uf/vf makes ulo==uhi false -> exact path decides.
__device__ __forceinline__ int resolve_pix(float bsf, float x, float y, float z) {
    float r  = norm_r(x, y, z);
    float zr = z * __builtin_amdgcn_rcpf(fmaxf(r, 1e-5f));
    // Guaranteed v-reject (threshold margin ~7e-5 rad >> all pipeline error).
    if (zr > 0.05240f || zr < -0.42270f) return -1;

    float ax = fabsf(x), ay = fabsf(y);
    float mx = fmaxf(ax, ay), mn = fminf(ax, ay);
    float t  = (mx > 0.0f) ? (mn * __builtin_amdgcn_rcpf(mx)) : 0.0f;
    float a  = fast_atan01(t);
    if (ay > ax) a = 1.5707963268f - a;
    if (x < 0.0f) a = 3.1415926536f - a;
    float th = (y < 0.0f) ? a : -a;             // ~= -atan2(y,x)

    float az  = fabsf(zr);
    float arg = az * __builtin_amdgcn_rsqf(FMAF(-zr, zr, 1.0f));
    float pa  = fast_atan01(arg);
    float ph  = (zr >= 0.0f) ? -pa : pa;        // ~= -asin(zr)

    float uf = (th - H0F) * (RHc * (float)W_IMG);
    float vf = (ph - V0F) * (RVc * (float)H_IMG);
    float ulo = floorf(uf - MU), uhi = floorf(uf + MU);
    float vlo = floorf(vf - MV), vhi = floorf(vf + MV);

    int u, v;
    if (ulo == uhi) {
        u = (int)ulo;
    } else {
        float theta = -glibc_atan2f(y, x);
        float u_n = __fmul_rn(__fsub_rn(theta, H0F), RHc);
        if (!(u_n >= 0.0f && u_n < 1.0f)) return -1;
        u = (int)__fmul_rn(u_n, (float)W_IMG);
    }
    if (u < 0 || u >= W_IMG) return -1;

    if (vlo == vhi) {
        v = (int)vlo;
    } else {
        // Recompute the BIT-EXACT zr the established exact pipeline uses.
        float zre = __fdiv_rn(z, fmaxf(r, 1e-5f));
        float s   = __fsqrt_rn(FMAF(-zre, zre, 1.0f));
        float d   = __fadd_rn(1.0f, s);
        float phi = -__fmul_rn(2.0f, glibc_atan2f(zre, d));
        float v_n = __fmul_rn(__fsub_rn(phi, V0F), RVc);
        if (!(v_n >= 0.0f && v_n < 1.0f)) return -1;
        v = (int)__fmul_rn(v_n, (float)H_IMG);
    }
    if (v < 0 || v >= H_IMG) return -1;

    return (((int)bsf) * H_IMG + v) * W_IMG + u;
}

// ---------------------------------------------------------------------------
// R17 scatter: R0's proven best structure (1 pt/thread, full grid, reverse
// order, monotone pre-read filter, single winner copy) + R16's thin resolve.
// Scatter-floor evidence (R10-R16): duration ~57-61us regardless of VALU
// (halved: no change), coherent-op count (halved: no change), MLP (4x: no
// change), scope (null). R0's filter variant was the best measured (57.5);
// restored here. Empty = negative (harness 0xAA-poisons d_ws each launch);
// monotone filter stale-safe; idempotent across replays.
// ---------------------------------------------------------------------------
#define SC_TPB 256

__global__ void __launch_bounds__(SC_TPB)
scatter_winner(const float* __restrict__ pts, int* __restrict__ winner, int n) {
    int t = blockIdx.x * blockDim.x + threadIdx.x;
    if (t >= n) return;
    int i = n - 1 - t;
    const float* q = pts + (size_t)i * 5;
    int pix = resolve_pix(q[0], q[1], q[2], q[3]);
    if (pix < 0) return;
    if (winner[pix] >= i) return;   // monotone filter (stale-safe)
    atomicMax(&winner[pix], i);
}

// ---------------------------------------------------------------------------
// R17/R18 write_output: REBUILT FOR MLP. The e2e-minus-scatter residual has
// been ~87us invariant across all rounds -> write_output (never profiled,
// never optimized) is the larger half. Old version: 1024 blocks (4 waves/
// SIMD) and 16 scalar scattered dword loads per thread -> latency-bound
// gather at quarter occupancy. New: 1 PIXEL/THREAD (4096 blocks, 16K waves,
// full 8 waves/SIMD resident), gather = two 8B memcpy loads (dwordx2 pairs,
// 4B-aligned-safe, same cacheline), 7 coalesced NT dword stores
// (lane-consecutive 256B/channel/wave). Same math as R0 (legacy fast
// features, err 2.4e-5 << 3.02 threshold).
// ---------------------------------------------------------------------------
__device__ __forceinline__ float atan01_legacy(float t) {
    float q = t * t;
    float p =          -0.0117212f;
    p = FMAF(q, p,      0.05265332f);
    p = FMAF(q, p,     -0.11643287f);
    p = FMAF(q, p,      0.19354346f);
    p = FMAF(q, p,     -0.33262347f);
    p = FMAF(q, p,      0.99997726f);
    return t * p;
}

__device__ __forceinline__ void fast_angles(float x, float y, float zr,
                                            float* theta, float* phi) {
    float ax = fabsf(x), ay = fabsf(y);
    float mx = fmaxf(ax, ay), mn = fminf(ax, ay);
    float t = (mx > 0.0f) ? (mn / mx) : 0.0f;
    float a = atan01_legacy(t);
    if (ay > ax) a = 1.57079632679f - a;
    if (x < 0.0f) a = 3.14159265359f - a;
    *theta = (y < 0.0f) ? a : -a;               // == -atan2(y,x)

    float az  = fabsf(zr);
    float arg = az / __fsqrt_rn(FMAF(-zr, zr, 1.0f));
    float pa  = atan01_legacy(arg);
    *phi = (zr >= 0.0f) ? -pa : pa;             // == -asin(zr)
}

typedef float v2f __attribute__((ext_vector_type(2)));

__global__ void __launch_bounds__(256)
write_output(const float* __restrict__ pts, const int* __restrict__ winner,
             float* __restrict__ out) {
    int p = blockIdx.x * blockDim.x + threadIdx.x;
    if (p >= NPIX) return;

    int wi = winner[p];

    float xv = 0.f, yv = 0.f, zv = 0.f, iv = 0.f;
    float rv = 0.f, th = 0.f, ph = 0.f;
    if (wi >= 0) {
        const float* qp = pts + (size_t)wi * 5 + 1;   // x,y,z,inten
        v2f q01, q23;
        __builtin_memcpy(&q01, qp + 0, sizeof(q01));  // dwordx2, 4B-align ok
        __builtin_memcpy(&q23, qp + 2, sizeof(q23));
        xv = q01.x; yv = q01.y; zv = q23.x; iv = q23.y;
        rv = norm_r(xv, yv, zv);
        float zr = __fdiv_rn(zv, fmaxf(rv, 1e-5f));
        fast_angles(xv, yv, zr, &th, &ph);
    }

    int b  = p >> 17;              // / HW_IMG (131072)
    int hw = p & (HW_IMG - 1);
    float* o = out + (size_t)b * C_IMG * HW_IMG + hw;
    __builtin_nontemporal_store(xv, o + 0 * HW_IMG);
    __builtin_nontemporal_store(yv, o + 1 * HW_IMG);
    __builtin_nontemporal_store(zv, o + 2 * HW_IMG);
    __builtin_nontemporal_store(rv, o + 3 * HW_IMG);
    __builtin_nontemporal_store(th, o + 4 * HW_IMG);
    __builtin_nontemporal_store(ph, o + 5 * HW_IMG);
    __builtin_nontemporal_store(iv, o + 6 * HW_IMG);
}

extern "C" void kernel_launch(void* const* d_in, const int* in_sizes, int n_in,
                              void* d_out, int out_size, void* d_ws, size_t ws_size,
                              hipStream_t stream) {
    const float* pts = (const float*)d_in[0];
    int n = in_sizes[0] / 5;
    if (n <= 0) return;
    int* winner = (int*)d_ws;   // 0xAA-poisoned each launch = negative = empty
    float* out = (float*)d_out;

    int blocks = (n + SC_TPB - 1) / SC_TPB;
    scatter_winner<<<blocks, SC_TPB, 0, stream>>>(pts, winner, n);

    int pblocks = (NPIX + 255) / 256;
    write_output<<<pblocks, 256, 0, stream>>>(pts, winner, out);
}